// Round 7
// baseline (14.892 us; speedup 1.0000x reference)
//
#include <hip/hip_runtime.h>
#include <float.h>

#define BB 256
#define VV 10475
#define RR 75
#define KK 5
#define RKN (RR * KK)     // 375 gathered points per array
#define NOUT (RR * RR)    // 5625 entries per batch
#define TI 3
#define TJ 3
#define NTI (RR / TI)     // 25
#define NTJ (RR / TJ)     // 25
#define NTILE (NTI * NTJ) // 625 active compute threads
#define TPB 768           // 12 waves: 750 gather threads, 625 compute threads

typedef __attribute__((__ext_vector_type__(2))) float f32x2;

__device__ __forceinline__ f32x2 pk_mul(f32x2 a, f32x2 b) {
    f32x2 d;
    asm("v_pk_mul_f32 %0, %1, %2" : "=v"(d) : "v"(a), "v"(b));
    return d;
}
__device__ __forceinline__ f32x2 pk_fma(f32x2 a, f32x2 b, f32x2 c) {
    f32x2 d;
    asm("v_pk_fma_f32 %0, %1, %2, %3" : "=v"(d) : "v"(a), "v"(b), "v"(c));
    return d;
}
__device__ __forceinline__ f32x2 mk2(float lo, float hi) {
    f32x2 r; r.x = lo; r.y = hi; return r;
}

__global__ __launch_bounds__(TPB) void ContactMap_47691316854895_kernel(
    const float* __restrict__ v1,
    const float* __restrict__ v2,
    const int* __restrict__ rid,
    float* __restrict__ out)
{
    // .xyz = point coords, .w = |point|^2 (computed once at gather time)
    __shared__ float4 g1s[RKN];   // 6 KB
    __shared__ float4 g2s[RKN];   // 6 KB

    const int b = blockIdx.x;
    const int tid = threadIdx.x;

    // Split gather: threads 0-374 -> v1, 375-749 -> v2.
    if (tid < RKN) {
        const int idx = rid[tid];
        const float* p = v1 + ((size_t)b * VV + idx) * 3;
        const float x = p[0], y = p[1], z = p[2];
        g1s[tid] = make_float4(x, y, z, x * x + y * y + z * z);
    } else if (tid < 2 * RKN) {
        const int t = tid - RKN;
        const int idx = rid[t];
        const float* p = v2 + ((size_t)b * VV + idx) * 3;
        const float x = p[0], y = p[1], z = p[2];
        g2s[t] = make_float4(x, y, z, x * x + y * y + z * z);
    }
    __syncthreads();

    if (tid >= NTILE) return;

    const int i0 = (tid / NTJ) * TI;
    const int j0 = (tid % NTJ) * TJ;

    // A-residues packed along p: pairs (p0,p1),(p2,p3) + scalar p4.
    f32x2 axp[TI][2], ayp[TI][2], azp[TI][2], awp[TI][2];
    float ax4[TI], ay4[TI], az4[TI], aw4[TI];
#pragma unroll
    for (int ii = 0; ii < TI; ++ii) {
        const float4 a0 = g1s[(i0 + ii) * KK + 0];
        const float4 a1 = g1s[(i0 + ii) * KK + 1];
        const float4 a2 = g1s[(i0 + ii) * KK + 2];
        const float4 a3 = g1s[(i0 + ii) * KK + 3];
        const float4 a4 = g1s[(i0 + ii) * KK + 4];
        axp[ii][0] = mk2(a0.x, a1.x); axp[ii][1] = mk2(a2.x, a3.x);
        ayp[ii][0] = mk2(a0.y, a1.y); ayp[ii][1] = mk2(a2.y, a3.y);
        azp[ii][0] = mk2(a0.z, a1.z); azp[ii][1] = mk2(a2.z, a3.z);
        awp[ii][0] = mk2(a0.w, a1.w); awp[ii][1] = mk2(a2.w, a3.w);
        ax4[ii] = a4.x; ay4[ii] = a4.y; az4[ii] = a4.z; aw4[ii] = a4.w;
    }

    const f32x2 neg2 = mk2(-2.0f, -2.0f);
    float* outb = out + (size_t)b * NOUT;

#pragma unroll
    for (int jj = 0; jj < TJ; ++jj) {
        // B coordinate splats (reused across the 3 ii's); bw stays scalar.
        f32x2 bxs[KK], bys[KK], bzs[KK];
        float bwv[KK];
#pragma unroll
        for (int q = 0; q < KK; ++q) {
            const float4 v = g2s[(j0 + jj) * KK + q];
            bxs[q] = mk2(v.x, v.x);
            bys[q] = mk2(v.y, v.y);
            bzs[q] = mk2(v.z, v.z);
            bwv[q] = v.w;
        }
#pragma unroll
        for (int ii = 0; ii < TI; ++ii) {
            float best = FLT_MAX;
#pragma unroll
            for (int q = 0; q < KK; ++q) {
                // Packed dots for p0..p3, scalar for p4.
                f32x2 zz01 = pk_mul(axp[ii][0], bxs[q]);
                zz01 = pk_fma(ayp[ii][0], bys[q], zz01);
                zz01 = pk_fma(azp[ii][0], bzs[q], zz01);
                f32x2 zz23 = pk_mul(axp[ii][1], bxs[q]);
                zz23 = pk_fma(ayp[ii][1], bys[q], zz23);
                zz23 = pk_fma(azp[ii][1], bzs[q], zz23);
                float zz4 = ax4[ii] * bxs[q].x;
                zz4 = fmaf(ay4[ii], bys[q].x, zz4);
                zz4 = fmaf(az4[ii], bzs[q].x, zz4);
                // t = aw[p] - 2*zz   (bw[q] hoisted out of the p-min)
                const f32x2 t01 = pk_fma(neg2, zz01, awp[ii][0]);
                const f32x2 t23 = pk_fma(neg2, zz23, awp[ii][1]);
                const float t4 = fmaf(-2.0f, zz4, aw4[ii]);
                const float m01 = fminf(t01.x, t01.y);
                const float m23 = fminf(t23.x, t23.y);
                const float m = fminf(fminf(m01, m23), t4);
                best = fminf(best, m + bwv[q]);
            }
            outb[(size_t)(i0 + ii) * RR + (j0 + jj)] = sqrtf(fmaxf(best, 0.0f));
        }
    }
}

extern "C" void kernel_launch(void* const* d_in, const int* in_sizes, int n_in,
                              void* d_out, int out_size, void* d_ws, size_t ws_size,
                              hipStream_t stream) {
    const float* v1 = (const float*)d_in[0];
    const float* v2 = (const float*)d_in[1];
    const int* rid = (const int*)d_in[2];
    float* out = (float*)d_out;

    ContactMap_47691316854895_kernel<<<dim3(BB), dim3(TPB), 0, stream>>>(v1, v2, rid, out);
}

// Round 8
// 13.275 us; speedup vs baseline: 1.1218x; 1.1218x over previous
//
#include <hip/hip_runtime.h>
#include <float.h>

#define BB 256
#define VV 10475
#define RR 75
#define KK 5
#define RKN (RR * KK)     // 375 gathered points per array
#define NOUT (RR * RR)    // 5625 entries per batch
#define TI 3
#define TJ 3
#define NTI (RR / TI)     // 25
#define NTJ (RR / TJ)     // 25
#define NTILE (NTI * NTJ) // 625 active compute threads
#define TPB 768           // 12 waves: 750 gather threads, 625 compute threads

__global__ __launch_bounds__(TPB) void ContactMap_47691316854895_kernel(
    const float* __restrict__ v1,
    const float* __restrict__ v2,
    const int* __restrict__ rid,
    float* __restrict__ out)
{
    // .xyz = point coords, .w = |point|^2 (computed once at gather time)
    __shared__ float4 g1s[RKN];   // 6 KB
    __shared__ float4 g2s[RKN];   // 6 KB

    const int b = blockIdx.x;
    const int tid = threadIdx.x;

    // Split gather: threads 0-374 -> v1, 375-749 -> v2.
    // 3 dependent scattered loads per thread; squared norm fused here.
    if (tid < RKN) {
        const int idx = rid[tid];
        const float* p = v1 + ((size_t)b * VV + idx) * 3;
        const float x = p[0], y = p[1], z = p[2];
        g1s[tid] = make_float4(x, y, z, x * x + y * y + z * z);
    } else if (tid < 2 * RKN) {
        const int t = tid - RKN;
        const int idx = rid[t];
        const float* p = v2 + ((size_t)b * VV + idx) * 3;
        const float x = p[0], y = p[1], z = p[2];
        g2s[t] = make_float4(x, y, z, x * x + y * y + z * z);
    }
    __syncthreads();

    if (tid >= NTILE) return;

    const int i0 = (tid / NTJ) * TI;
    const int j0 = (tid % NTJ) * TJ;

    // Hoist the 3 a-residues (15 points + norms) into registers.
    float ax[TI][KK], ay[TI][KK], az[TI][KK], aw[TI][KK];
#pragma unroll
    for (int ii = 0; ii < TI; ++ii) {
#pragma unroll
        for (int p = 0; p < KK; ++p) {
            const float4 a = g1s[(i0 + ii) * KK + p];
            ax[ii][p] = a.x; ay[ii][p] = a.y; az[ii][p] = a.z; aw[ii][p] = a.w;
        }
    }

    float* outb = out + (size_t)b * NOUT;

#pragma unroll
    for (int jj = 0; jj < TJ; ++jj) {
        float bx[KK], by[KK], bz[KK], bw[KK];
#pragma unroll
        for (int q = 0; q < KK; ++q) {
            const float4 v = g2s[(j0 + jj) * KK + q];
            bx[q] = v.x; by[q] = v.y; bz[q] = v.z; bw[q] = v.w;
        }
#pragma unroll
        for (int ii = 0; ii < TI; ++ii) {
            float best = FLT_MAX;
#pragma unroll
            for (int p = 0; p < KK; ++p) {
                float bq = FLT_MAX;
#pragma unroll
                for (int q = 0; q < KK; ++q) {
                    float zz = ax[ii][p] * bx[q];
                    zz = fmaf(ay[ii][p], by[q], zz);
                    zz = fmaf(az[ii][p], bz[q], zz);
                    // ry - 2*z  (rx added once per p below)
                    bq = fminf(bq, fmaf(-2.0f, zz, bw[q]));
                }
                best = fminf(best, aw[ii][p] + bq);
            }
            outb[(size_t)(i0 + ii) * RR + (j0 + jj)] = sqrtf(fmaxf(best, 0.0f));
        }
    }
}

extern "C" void kernel_launch(void* const* d_in, const int* in_sizes, int n_in,
                              void* d_out, int out_size, void* d_ws, size_t ws_size,
                              hipStream_t stream) {
    const float* v1 = (const float*)d_in[0];
    const float* v2 = (const float*)d_in[1];
    const int* rid = (const int*)d_in[2];
    float* out = (float*)d_out;

    ContactMap_47691316854895_kernel<<<dim3(BB), dim3(TPB), 0, stream>>>(v1, v2, rid, out);
}